// Round 1
// baseline (389.784 us; speedup 1.0000x reference)
//
#include <hip/hip_runtime.h>
#include <hip/hip_bf16.h>

// ---------------------------------------------------------------------------
// Mlp_FMoE: fc1(MoE 2-expert, top-1) -> DWConv3x3 -> GELU(exact) -> fc2(MoE)
// B=16 N=1024 C=512 Dh=2048 H=W=32, all inputs fp32, output fp32.
//
// Precision plan:
//  - gates fp32 (layer2 via deterministic chunk partials) -> match np argmax
//  - fc1 split-bf16 (bf16x3) -> h accurate to ~4e-6 rel (gate-safe)
//  - shift_quant via double log2 (boundary-safe), exact powers of 2 in bf16
//  - conv+gelu fp32; fc2 plain bf16 (output tol 2%)
// ---------------------------------------------------------------------------

#define TOKS  16384
#define CIN   512
#define DHID  2048

typedef __attribute__((ext_vector_type(8))) __bf16 bf16x8;
typedef __attribute__((ext_vector_type(4))) float  f32x4;
typedef __attribute__((ext_vector_type(4))) float  float4v;
typedef __attribute__((ext_vector_type(4))) unsigned short ushort4v;

__device__ __forceinline__ unsigned short f2bf(float f) {
  union { float f; unsigned int u; } a; a.f = f;
  unsigned int u = a.u;
  unsigned int r = u + 0x7FFFu + ((u >> 16) & 1u);   // RNE
  return (unsigned short)(r >> 16);
}
__device__ __forceinline__ float bf2f(unsigned short h) {
  union { unsigned int u; float f; } a; a.u = ((unsigned int)h) << 16;
  return a.f;
}

// shift_quant: sign(w) * 2^clip(round(log2(|w|+1e-12)), -14, 0)
// double log2 so round-half-even decisions match the true value (np-safe).
__device__ __forceinline__ float squant(float w) {
  float aw = fabsf(w) + 1e-12f;          // fp32 add, as reference
  double l = log2((double)aw);
  double r = rint(l);
  r = fmin(fmax(r, -14.0), 0.0);
  float q = exp2f((float)r);             // exact power of two
  return (w > 0.0f) ? q : ((w < 0.0f) ? -q : 0.0f);
}

#define GLDS16(gp, lp) __builtin_amdgcn_global_load_lds(                      \
    (const __attribute__((address_space(1))) void*)(gp),                      \
    (__attribute__((address_space(3))) void*)(lp), 16, 0, 0)

// ------------------------- weight prep -------------------------------------
__global__ void k_prep(const float* __restrict__ w0, const float* __restrict__ w1,
                       const float* __restrict__ w20, const float* __restrict__ w21,
                       unsigned short* __restrict__ w0hi, unsigned short* __restrict__ w0lo,
                       unsigned short* __restrict__ w1q, unsigned short* __restrict__ w20b,
                       unsigned short* __restrict__ w21b) {
  int i = blockIdx.x * 256 + threadIdx.x;
  if (i >= DHID * CIN) return;
  float v = w0[i];
  unsigned short h = f2bf(v);
  w0hi[i] = h;
  w0lo[i] = f2bf(v - bf2f(h));
  w1q[i]  = f2bf(squant(w1[i]));    // exact
  w20b[i] = f2bf(w20[i]);
  w21b[i] = f2bf(squant(w21[i]));   // exact
}

// ------------------------- gate 1 (fp32 exact) ------------------------------
__global__ void k_gate1(const float* __restrict__ x, const float* __restrict__ wg1,
                        unsigned char* __restrict__ pick1) {
  int tok = blockIdx.x * 4 + (threadIdx.x >> 6);
  int l = threadIdx.x & 63;
  const float* xr = x + (size_t)tok * CIN;
  float s0 = 0.f, s1 = 0.f;
  for (int i = l; i < CIN; i += 64) {
    float v = xr[i];
    s0 += v * wg1[i * 2 + 0];
    s1 += v * wg1[i * 2 + 1];
  }
  for (int m = 32; m; m >>= 1) { s0 += __shfl_xor(s0, m); s1 += __shfl_xor(s1, m); }
  if (l == 0) pick1[tok] = (s0 >= s1) ? 0 : 1;   // argmax==0 on tie
}

// ------------------------- fc1: split-bf16 MoE GEMM -------------------------
// tile 128 tok x 128 d, BK=32, 4 waves (64x64 each), 16x16x32 bf16 MFMA.
// acc0 = xh*w0h + xl*w0h + xh*w0l ; acc1 = xh*w1q + xl*w1q
__launch_bounds__(256, 2)
__global__ void k_fc1(const float* __restrict__ x,
                      const unsigned short* __restrict__ w0hi,
                      const unsigned short* __restrict__ w0lo,
                      const unsigned short* __restrict__ w1q,
                      const float* __restrict__ b0, const float* __restrict__ b1,
                      const unsigned char* __restrict__ pick1,
                      float* __restrict__ h32) {
  __shared__ unsigned short lAh[128][40];   // +8 pad: conflict-light reads
  __shared__ unsigned short lAl[128][40];
  __shared__ unsigned short lB0h[128][32];  // linear (global_load_lds dest)
  __shared__ unsigned short lB0l[128][32];
  __shared__ unsigned short lB1q[128][32];

  const int t = threadIdx.x;
  const int wv = t >> 6, ln = t & 63;
  const int lr = ln & 15, lg = ln >> 4;
  const int tok0 = blockIdx.x * 128;
  const int nbase = blockIdx.y * 128;
  const int wm = (wv >> 1) * 64, wn = (wv & 1) * 64;

  f32x4 acc0[4][4], acc1[4][4];
  #pragma unroll
  for (int i = 0; i < 4; ++i)
    #pragma unroll
    for (int j = 0; j < 4; ++j) {
      acc0[i][j] = f32x4{0.f, 0.f, 0.f, 0.f};
      acc1[i][j] = f32x4{0.f, 0.f, 0.f, 0.f};
    }

  for (int kt = 0; kt < CIN / 32; ++kt) {
    const int k0 = kt * 32;
    // A (fp32) to regs — issued before barrier, latency overlaps prev compute
    float4v av[4];
    #pragma unroll
    for (int p = 0; p < 4; ++p) {
      int idx = p * 256 + t;
      int row = idx >> 3;
      int c4 = (idx & 7) << 2;
      av[p] = *(const float4v*)(x + (size_t)(tok0 + row) * CIN + k0 + c4);
    }
    __syncthreads();   // prev iteration's LDS reads done
    // B tiles: async DMA, 16B/lane, wave-uniform LDS base
    #pragma unroll
    for (int s = 0; s < 2; ++s) {
      int rowblk = s * 4 + wv;                  // uniform per wave
      int row = (rowblk << 4) + (ln >> 2);
      int cg = (ln & 3) << 3;
      size_t go = (size_t)(nbase + row) * CIN + k0 + cg;
      GLDS16(w0hi + go, &lB0h[rowblk << 4][0]);
      GLDS16(w0lo + go, &lB0l[rowblk << 4][0]);
      GLDS16(w1q + go, &lB1q[rowblk << 4][0]);
    }
    // A split hi/lo -> LDS
    #pragma unroll
    for (int p = 0; p < 4; ++p) {
      int idx = p * 256 + t;
      int row = idx >> 3;
      int c4 = (idx & 7) << 2;
      ushort4v hv, lv;
      #pragma unroll
      for (int q = 0; q < 4; ++q) {
        float v = av[p][q];
        unsigned short h = f2bf(v);
        hv[q] = h;
        lv[q] = f2bf(v - bf2f(h));
      }
      *(ushort4v*)(&lAh[row][c4]) = hv;
      *(ushort4v*)(&lAl[row][c4]) = lv;
    }
    __syncthreads();   // drains vmcnt (DMA) + lgkm (A writes)

    bf16x8 ah[4], al[4];
    #pragma unroll
    for (int mt = 0; mt < 4; ++mt) {
      ah[mt] = *(const bf16x8*)(&lAh[wm + (mt << 4) + lr][lg << 3]);
      al[mt] = *(const bf16x8*)(&lAl[wm + (mt << 4) + lr][lg << 3]);
    }
    #pragma unroll
    for (int nt = 0; nt < 4; ++nt) {
      bf16x8 bh = *(const bf16x8*)(&lB0h[wn + (nt << 4) + lr][lg << 3]);
      bf16x8 bl = *(const bf16x8*)(&lB0l[wn + (nt << 4) + lr][lg << 3]);
      bf16x8 bq = *(const bf16x8*)(&lB1q[wn + (nt << 4) + lr][lg << 3]);
      #pragma unroll
      for (int mt = 0; mt < 4; ++mt) {
        acc0[mt][nt] = __builtin_amdgcn_mfma_f32_16x16x32_bf16(ah[mt], bh, acc0[mt][nt], 0, 0, 0);
        acc0[mt][nt] = __builtin_amdgcn_mfma_f32_16x16x32_bf16(al[mt], bh, acc0[mt][nt], 0, 0, 0);
        acc0[mt][nt] = __builtin_amdgcn_mfma_f32_16x16x32_bf16(ah[mt], bl, acc0[mt][nt], 0, 0, 0);
        acc1[mt][nt] = __builtin_amdgcn_mfma_f32_16x16x32_bf16(ah[mt], bq, acc1[mt][nt], 0, 0, 0);
        acc1[mt][nt] = __builtin_amdgcn_mfma_f32_16x16x32_bf16(al[mt], bq, acc1[mt][nt], 0, 0, 0);
      }
    }
  }
  // epilogue: per-row expert select + bias, fp32 store
  #pragma unroll
  for (int nt = 0; nt < 4; ++nt) {
    int d = nbase + wn + (nt << 4) + lr;
    float bi0 = b0[d], bi1 = b1[d];
    #pragma unroll
    for (int mt = 0; mt < 4; ++mt) {
      f32x4 v0 = acc0[mt][nt], v1 = acc1[mt][nt];
      #pragma unroll
      for (int rr = 0; rr < 4; ++rr) {
        int tok = tok0 + wm + (mt << 4) + (lg << 2) + rr;
        float val = pick1[tok] ? (v1[rr] + bi1) : (v0[rr] + bi0);
        h32[(size_t)tok * DHID + d] = val;
      }
    }
  }
}

// ---------------- DWConv3x3 + bias + exact GELU + gate2 partials ------------
// block: (dchunk 32, ystrip 8, image b). LDS [10 rows][32 x][32 d] fp32.
__global__ void k_conv(const float* __restrict__ h32, const float* __restrict__ dww,
                       const float* __restrict__ dwb, const float* __restrict__ wg2,
                       unsigned short* __restrict__ hb, float* __restrict__ part) {
  __shared__ float tile[10][32][32];
  const int dc = blockIdx.x;   // 0..63
  const int ys = blockIdx.y;   // 0..3
  const int b  = blockIdx.z;   // 0..15
  const int t = threadIdx.x;
  const int d0 = dc * 32, y0 = ys * 8;

  for (int p = 0; p < 10240; p += 256) {
    int idx = p + t;
    int dl = idx & 31, xx = (idx >> 5) & 31, ry = idx >> 10;
    int y = y0 - 1 + ry;
    float v = 0.f;
    if (y >= 0 && y < 32)
      v = h32[(size_t)(b * 1024 + y * 32 + xx) * DHID + d0 + dl];
    tile[ry][xx][dl] = v;
  }
  __syncthreads();

  const int dl = t & 31, xg = t >> 5;
  const int d = d0 + dl;
  float kk[9];
  #pragma unroll
  for (int i = 0; i < 9; ++i) kk[i] = dww[d * 9 + i];
  const float bias = dwb[d];
  const float g0 = wg2[d * 2 + 0], g1 = wg2[d * 2 + 1];

  for (int yy = 0; yy < 8; ++yy) {
    int ry = yy + 1;
    #pragma unroll
    for (int xi = 0; xi < 4; ++xi) {
      int xx = xg * 4 + xi;
      float s = bias;
      #pragma unroll
      for (int dy = -1; dy <= 1; ++dy)
        #pragma unroll
        for (int dx = -1; dx <= 1; ++dx) {
          int xs = xx + dx;
          float v = (xs >= 0 && xs < 32) ? tile[ry + dy][xs][dl] : 0.f;
          s += v * kk[(dy + 1) * 3 + (dx + 1)];
        }
      float gg = 0.5f * s * (1.0f + erff(s * 0.70710678118654752f));  // exact gelu
      int tok = b * 1024 + (y0 + yy) * 32 + xx;
      hb[(size_t)tok * DHID + d] = f2bf(gg);
      // deterministic gate2 partial over this 32-d chunk (32-lane tree)
      float p0 = gg * g0, p1 = gg * g1;
      for (int m = 16; m; m >>= 1) { p0 += __shfl_xor(p0, m); p1 += __shfl_xor(p1, m); }
      if (dl == 0) {
        part[(size_t)tok * 128 + 0 * 64 + dc] = p0;
        part[(size_t)tok * 128 + 1 * 64 + dc] = p1;
      }
    }
  }
}

// ------------------------- gate 2 reduce ------------------------------------
__global__ void k_gate2(const float* __restrict__ part, unsigned char* __restrict__ pick2) {
  int tok = blockIdx.x * 256 + threadIdx.x;
  const float* pr = part + (size_t)tok * 128;
  float s0 = 0.f, s1 = 0.f;
  for (int i = 0; i < 64; ++i) { s0 += pr[i]; s1 += pr[64 + i]; }
  pick2[tok] = (s0 >= s1) ? 0 : 1;
}

// ------------------------- fc2: bf16 MoE GEMM -------------------------------
__launch_bounds__(256, 2)
__global__ void k_fc2(const unsigned short* __restrict__ hb,
                      const unsigned short* __restrict__ w20b,
                      const unsigned short* __restrict__ w21b,
                      const float* __restrict__ b0, const float* __restrict__ b1,
                      const unsigned char* __restrict__ pick2,
                      float* __restrict__ out) {
  __shared__ unsigned short lA[128][32];
  __shared__ unsigned short lB0[128][32];
  __shared__ unsigned short lB1[128][32];
  const int t = threadIdx.x;
  const int wv = t >> 6, ln = t & 63;
  const int lr = ln & 15, lg = ln >> 4;
  const int tok0 = blockIdx.x * 128;
  const int nbase = blockIdx.y * 128;
  const int wm = (wv >> 1) * 64, wn = (wv & 1) * 64;

  f32x4 acc0[4][4], acc1[4][4];
  #pragma unroll
  for (int i = 0; i < 4; ++i)
    #pragma unroll
    for (int j = 0; j < 4; ++j) {
      acc0[i][j] = f32x4{0.f, 0.f, 0.f, 0.f};
      acc1[i][j] = f32x4{0.f, 0.f, 0.f, 0.f};
    }

  for (int kt = 0; kt < DHID / 32; ++kt) {
    const int k0 = kt * 32;
    __syncthreads();
    #pragma unroll
    for (int s = 0; s < 2; ++s) {
      int rowblk = s * 4 + wv;
      int row = (rowblk << 4) + (ln >> 2);
      int cg = (ln & 3) << 3;
      size_t goA = (size_t)(tok0 + row) * DHID + k0 + cg;
      size_t goB = (size_t)(nbase + row) * DHID + k0 + cg;
      GLDS16(hb + goA, &lA[rowblk << 4][0]);
      GLDS16(w20b + goB, &lB0[rowblk << 4][0]);
      GLDS16(w21b + goB, &lB1[rowblk << 4][0]);
    }
    __syncthreads();
    bf16x8 a[4];
    #pragma unroll
    for (int mt = 0; mt < 4; ++mt)
      a[mt] = *(const bf16x8*)(&lA[wm + (mt << 4) + lr][lg << 3]);
    #pragma unroll
    for (int nt = 0; nt < 4; ++nt) {
      bf16x8 b0f = *(const bf16x8*)(&lB0[wn + (nt << 4) + lr][lg << 3]);
      bf16x8 b1f = *(const bf16x8*)(&lB1[wn + (nt << 4) + lr][lg << 3]);
      #pragma unroll
      for (int mt = 0; mt < 4; ++mt) {
        acc0[mt][nt] = __builtin_amdgcn_mfma_f32_16x16x32_bf16(a[mt], b0f, acc0[mt][nt], 0, 0, 0);
        acc1[mt][nt] = __builtin_amdgcn_mfma_f32_16x16x32_bf16(a[mt], b1f, acc1[mt][nt], 0, 0, 0);
      }
    }
  }
  #pragma unroll
  for (int nt = 0; nt < 4; ++nt) {
    int c = nbase + wn + (nt << 4) + lr;
    float bi0 = b0[c], bi1 = b1[c];
    #pragma unroll
    for (int mt = 0; mt < 4; ++mt) {
      f32x4 v0 = acc0[mt][nt], v1 = acc1[mt][nt];
      #pragma unroll
      for (int rr = 0; rr < 4; ++rr) {
        int tok = tok0 + wm + (mt << 4) + (lg << 2) + rr;
        float val = pick2[tok] ? (v1[rr] + bi1) : (v0[rr] + bi0);
        out[(size_t)tok * CIN + c] = val;
      }
    }
  }
}

// ---------------------------------------------------------------------------
extern "C" void kernel_launch(void* const* d_in, const int* in_sizes, int n_in,
                              void* d_out, int out_size, void* d_ws, size_t ws_size,
                              hipStream_t stream) {
  (void)in_sizes; (void)n_in; (void)out_size; (void)ws_size;
  const float* x   = (const float*)d_in[0];
  const float* wg1 = (const float*)d_in[3];
  const float* w0  = (const float*)d_in[4];
  const float* b0  = (const float*)d_in[5];
  const float* w1  = (const float*)d_in[6];
  const float* b1  = (const float*)d_in[7];
  const float* dww = (const float*)d_in[8];
  const float* dwb = (const float*)d_in[9];
  const float* wg2 = (const float*)d_in[10];
  const float* w20 = (const float*)d_in[11];
  const float* b20 = (const float*)d_in[12];
  const float* w21 = (const float*)d_in[13];
  const float* b21 = (const float*)d_in[14];
  float* out = (float*)d_out;

  char* ws = (char*)d_ws;
  const size_t MB2 = 1u << 21;   // 2 MiB per weight buffer (2048*512*2B)
  unsigned short* w0hi = (unsigned short*)(ws + 0 * MB2);
  unsigned short* w0lo = (unsigned short*)(ws + 1 * MB2);
  unsigned short* w1q  = (unsigned short*)(ws + 2 * MB2);
  unsigned short* w20b = (unsigned short*)(ws + 3 * MB2);
  unsigned short* w21b = (unsigned short*)(ws + 4 * MB2);
  unsigned char* pick1 = (unsigned char*)(ws + 5 * MB2);
  unsigned char* pick2 = (unsigned char*)(ws + 5 * MB2 + 65536);
  float* part = (float*)(ws + 5 * MB2 + 131072);                        // 8 MB
  float* h32  = (float*)(ws + 5 * MB2 + 131072 + (size_t)TOKS * 128 * 4);
  unsigned short* hb = (unsigned short*)((char*)h32 + (size_t)TOKS * DHID * 4);
  // total ws use: ~210 MiB

  k_prep <<<4096, 256, 0, stream>>>(w0, w1, w20, w21, w0hi, w0lo, w1q, w20b, w21b);
  k_gate1<<<4096, 256, 0, stream>>>(x, wg1, pick1);
  k_fc1  <<<dim3(128, 16), 256, 0, stream>>>(x, w0hi, w0lo, w1q, b0, b1, pick1, h32);
  k_conv <<<dim3(64, 4, 16), 256, 0, stream>>>(h32, dww, dwb, wg2, hb, part);
  k_gate2<<<64, 256, 0, stream>>>(part, pick2);
  k_fc2  <<<dim3(128, 4), 256, 0, stream>>>(hb, w20b, w21b, b20, b21, pick2, out);
}

// Round 2
// 373.450 us; speedup vs baseline: 1.0437x; 1.0437x over previous
//
#include <hip/hip_runtime.h>
#include <hip/hip_bf16.h>

// ---------------------------------------------------------------------------
// Mlp_FMoE: fc1(MoE 2-expert top-1) -> DWConv3x3 -> GELU(exact) -> fc2(MoE)
// B=16 N=1024 C=512 Dh=2048 H=W=32, fp32 in/out.
// R2: token-gather per expert (halves MFMA work), B-tile XOR swizzle
//     (kills 8-way bank conflict), frexp-exact squant (drops fp64).
// ---------------------------------------------------------------------------

#define TOKS  16384
#define CIN   512
#define DHID  2048

typedef __attribute__((ext_vector_type(8))) __bf16 bf16x8;
typedef __attribute__((ext_vector_type(4))) float  f32x4;
typedef __attribute__((ext_vector_type(4))) float  float4v;
typedef __attribute__((ext_vector_type(4))) unsigned short ushort4v;

__device__ __forceinline__ unsigned short f2bf(float f) {
  union { float f; unsigned int u; } a; a.f = f;
  unsigned int u = a.u;
  unsigned int r = u + 0x7FFFu + ((u >> 16) & 1u);   // RNE
  return (unsigned short)(r >> 16);
}
__device__ __forceinline__ float bf2f(unsigned short h) {
  union { unsigned int u; float f; } a; a.u = ((unsigned int)h) << 16;
  return a.f;
}

// shift_quant: sign(w)*2^clip(round(log2(|w|+1e-12)),-14,0).
// round(log2(aw)) == e + (mantissa > sqrt(2)); boundary exact via bit test
// (log2 of a float is never exactly k+0.5, so RNE tie-break is moot).
__device__ __forceinline__ float squant(float w) {
  if (w == 0.0f) return 0.0f;
  float aw = fabsf(w) + 1e-12f;                 // fp32 add, as reference
  union { float f; unsigned u; } a; a.f = aw;
  int e = (int)((a.u >> 23) & 0xFFu) - 127;
  unsigned frac = a.u & 0x7FFFFFu;
  int shift = e + (frac >= 0x3504F4u ? 1 : 0);  // 0x3504F4: first frac with m>sqrt2
  shift = min(max(shift, -14), 0);
  union { unsigned u; float f; } q; q.u = (unsigned)(shift + 127) << 23;
  return (w > 0.0f) ? q.f : -q.f;
}

#define GLDS16(gp, lp) __builtin_amdgcn_global_load_lds(                      \
    (const __attribute__((address_space(1))) void*)(gp),                      \
    (__attribute__((address_space(3))) void*)(lp), 16, 0, 0)

// ------------------------- weight prep -------------------------------------
__global__ void k_prep(const float* __restrict__ w0, const float* __restrict__ w1,
                       const float* __restrict__ w20, const float* __restrict__ w21,
                       unsigned short* __restrict__ w0hi, unsigned short* __restrict__ w0lo,
                       unsigned short* __restrict__ w1q, unsigned short* __restrict__ w20b,
                       unsigned short* __restrict__ w21b) {
  int i = blockIdx.x * 256 + threadIdx.x;
  if (i >= DHID * CIN) return;
  float v = w0[i];
  unsigned short h = f2bf(v);
  w0hi[i] = h;
  w0lo[i] = f2bf(v - bf2f(h));
  w1q[i]  = f2bf(squant(w1[i]));    // exact power of two -> exact in bf16
  w20b[i] = f2bf(w20[i]);
  w21b[i] = f2bf(squant(w21[i]));
}

// ------------------------- gate 1 (fp32 exact) ------------------------------
__global__ void k_gate1(const float* __restrict__ x, const float* __restrict__ wg1,
                        unsigned char* __restrict__ pick1) {
  int tok = blockIdx.x * 4 + (threadIdx.x >> 6);
  int l = threadIdx.x & 63;
  const float* xr = x + (size_t)tok * CIN;
  float s0 = 0.f, s1 = 0.f;
  for (int i = l; i < CIN; i += 64) {
    float v = xr[i];
    s0 += v * wg1[i * 2 + 0];
    s1 += v * wg1[i * 2 + 1];
  }
  for (int m = 32; m; m >>= 1) { s0 += __shfl_xor(s0, m); s1 += __shfl_xor(s1, m); }
  if (l == 0) pick1[tok] = (s0 >= s1) ? 0 : 1;   // argmax==0 on tie
}

// --------------- stable partition: perm = [expert0 toks..., expert1 toks...]
__global__ void k_scan(const unsigned char* __restrict__ pick, int* __restrict__ perm,
                       int* __restrict__ n0buf) {
  __shared__ int cnt[1024];
  const int t = threadIdx.x;
  unsigned char loc[16];
  int c0 = 0;
  #pragma unroll
  for (int i = 0; i < 16; ++i) { loc[i] = pick[t * 16 + i]; c0 += (loc[i] == 0); }
  cnt[t] = c0;
  __syncthreads();
  for (int off = 1; off < 1024; off <<= 1) {
    int v = cnt[t] + ((t >= off) ? cnt[t - off] : 0);
    __syncthreads();
    cnt[t] = v;
    __syncthreads();
  }
  int total0 = cnt[1023];
  int pre0 = cnt[t] - c0;
  int pre1 = t * 16 - pre0;
  if (t == 0) n0buf[0] = total0;
  int p0 = pre0, p1 = total0 + pre1;
  #pragma unroll
  for (int i = 0; i < 16; ++i) {
    int tok = t * 16 + i;
    if (loc[i] == 0) perm[p0++] = tok; else perm[p1++] = tok;
  }
}

// ------------------------- fc1: gathered split-bf16 MoE GEMM ----------------
// tile 128 tok x 128 d, BK=32, 4 waves. Rows are perm-gathered; tiles fully in
// one expert run only that expert's chains (3 for dense, 2 for shift).
__launch_bounds__(256, 2)
__global__ void k_fc1(const float* __restrict__ x,
                      const unsigned short* __restrict__ w0hi,
                      const unsigned short* __restrict__ w0lo,
                      const unsigned short* __restrict__ w1q,
                      const float* __restrict__ b0, const float* __restrict__ b1,
                      const int* __restrict__ perm, const int* __restrict__ n0buf,
                      float* __restrict__ h32) {
  __shared__ unsigned short lAh[128][40];   // +8 pad (ds_write path)
  __shared__ unsigned short lAl[128][40];
  __shared__ unsigned short lB0h[128][32];  // linear rows, XOR-swizzled slots
  __shared__ unsigned short lB0l[128][32];
  __shared__ unsigned short lB1q[128][32];

  const int t = threadIdx.x;
  const int wv = t >> 6, ln = t & 63;
  const int lr = ln & 15, lg = ln >> 4;
  const int tok0 = blockIdx.x * 128;
  const int nbase = blockIdx.y * 128;
  const int wm = (wv >> 1) * 64, wn = (wv & 1) * 64;
  const int n0 = n0buf[0];
  const bool do0 = (tok0 < n0);          // tile contains expert0 rows
  const bool do1 = (tok0 + 128 > n0);    // tile contains expert1 rows

  int prow[4];
  #pragma unroll
  for (int p = 0; p < 4; ++p) prow[p] = perm[tok0 + ((p * 256 + t) >> 3)];

  // swizzle: LDS slot s of row r holds global col-block s ^ ((r>>1)&3)
  const int swsrc = ((ln & 3) ^ ((ln >> 3) & 3)) << 3;   // ushort offset (source side)
  const int swrd  = (lg ^ ((lr >> 1) & 3)) << 3;         // ushort offset (read side)

  f32x4 acc0[4][4], acc1[4][4];
  #pragma unroll
  for (int i = 0; i < 4; ++i)
    #pragma unroll
    for (int j = 0; j < 4; ++j) {
      acc0[i][j] = f32x4{0.f, 0.f, 0.f, 0.f};
      acc1[i][j] = f32x4{0.f, 0.f, 0.f, 0.f};
    }

  for (int kt = 0; kt < CIN / 32; ++kt) {
    const int k0 = kt * 32;
    float4v av[4];
    #pragma unroll
    for (int p = 0; p < 4; ++p) {
      int idx = p * 256 + t;
      av[p] = *(const float4v*)(x + (size_t)prow[p] * CIN + k0 + ((idx & 7) << 2));
    }
    __syncthreads();   // prev iteration's LDS reads done
    #pragma unroll
    for (int s = 0; s < 2; ++s) {
      int rowblk = s * 4 + wv;                  // wave-uniform LDS base
      int row = (rowblk << 4) + (ln >> 2);
      size_t go = (size_t)(nbase + row) * CIN + k0 + swsrc;
      if (do0) {
        GLDS16(w0hi + go, &lB0h[rowblk << 4][0]);
        GLDS16(w0lo + go, &lB0l[rowblk << 4][0]);
      }
      if (do1) GLDS16(w1q + go, &lB1q[rowblk << 4][0]);
    }
    #pragma unroll
    for (int p = 0; p < 4; ++p) {
      int idx = p * 256 + t;
      int row = idx >> 3, c4 = (idx & 7) << 2;
      ushort4v hv, lv;
      #pragma unroll
      for (int q = 0; q < 4; ++q) {
        float v = av[p][q];
        unsigned short h = f2bf(v);
        hv[q] = h;
        lv[q] = f2bf(v - bf2f(h));
      }
      *(ushort4v*)(&lAh[row][c4]) = hv;
      *(ushort4v*)(&lAl[row][c4]) = lv;
    }
    __syncthreads();   // drains vmcnt(DMA) + lgkm(A writes)

    bf16x8 ah[4], al[4];
    #pragma unroll
    for (int mt = 0; mt < 4; ++mt) {
      ah[mt] = *(const bf16x8*)(&lAh[wm + (mt << 4) + lr][lg << 3]);
      al[mt] = *(const bf16x8*)(&lAl[wm + (mt << 4) + lr][lg << 3]);
    }
    #pragma unroll
    for (int nt = 0; nt < 4; ++nt) {
      int rB = wn + (nt << 4) + lr;
      if (do0) {
        bf16x8 bh = *(const bf16x8*)(&lB0h[rB][swrd]);
        bf16x8 bl = *(const bf16x8*)(&lB0l[rB][swrd]);
        #pragma unroll
        for (int mt = 0; mt < 4; ++mt) {
          acc0[mt][nt] = __builtin_amdgcn_mfma_f32_16x16x32_bf16(ah[mt], bh, acc0[mt][nt], 0, 0, 0);
          acc0[mt][nt] = __builtin_amdgcn_mfma_f32_16x16x32_bf16(al[mt], bh, acc0[mt][nt], 0, 0, 0);
          acc0[mt][nt] = __builtin_amdgcn_mfma_f32_16x16x32_bf16(ah[mt], bl, acc0[mt][nt], 0, 0, 0);
        }
      }
      if (do1) {
        bf16x8 bq = *(const bf16x8*)(&lB1q[rB][swrd]);
        #pragma unroll
        for (int mt = 0; mt < 4; ++mt) {
          acc1[mt][nt] = __builtin_amdgcn_mfma_f32_16x16x32_bf16(ah[mt], bq, acc1[mt][nt], 0, 0, 0);
          acc1[mt][nt] = __builtin_amdgcn_mfma_f32_16x16x32_bf16(al[mt], bq, acc1[mt][nt], 0, 0, 0);
        }
      }
    }
  }
  // epilogue: expert by partition position, scatter through perm
  #pragma unroll
  for (int nt = 0; nt < 4; ++nt) {
    int d = nbase + wn + (nt << 4) + lr;
    float bi0 = b0[d], bi1 = b1[d];
    #pragma unroll
    for (int mt = 0; mt < 4; ++mt) {
      f32x4 v0 = acc0[mt][nt], v1 = acc1[mt][nt];
      #pragma unroll
      for (int rr = 0; rr < 4; ++rr) {
        int pos = tok0 + wm + (mt << 4) + (lg << 2) + rr;
        int tok = perm[pos];
        float val = (pos >= n0) ? (v1[rr] + bi1) : (v0[rr] + bi0);
        h32[(size_t)tok * DHID + d] = val;
      }
    }
  }
}

// ---------------- DWConv3x3 + bias + exact GELU + gate2 partials ------------
__global__ void k_conv(const float* __restrict__ h32, const float* __restrict__ dww,
                       const float* __restrict__ dwb, const float* __restrict__ wg2,
                       unsigned short* __restrict__ hb, float* __restrict__ part) {
  __shared__ float tile[10][32][32];
  const int dc = blockIdx.x;   // 0..63
  const int ys = blockIdx.y;   // 0..3
  const int b  = blockIdx.z;   // 0..15
  const int t = threadIdx.x;
  const int d0 = dc * 32, y0 = ys * 8;

  for (int p = 0; p < 10240; p += 256) {
    int idx = p + t;
    int dl = idx & 31, xx = (idx >> 5) & 31, ry = idx >> 10;
    int y = y0 - 1 + ry;
    float v = 0.f;
    if (y >= 0 && y < 32)
      v = h32[(size_t)(b * 1024 + y * 32 + xx) * DHID + d0 + dl];
    tile[ry][xx][dl] = v;
  }
  __syncthreads();

  const int dl = t & 31, xg = t >> 5;
  const int d = d0 + dl;
  float kk[9];
  #pragma unroll
  for (int i = 0; i < 9; ++i) kk[i] = dww[d * 9 + i];
  const float bias = dwb[d];
  const float g0 = wg2[d * 2 + 0], g1 = wg2[d * 2 + 1];

  for (int yy = 0; yy < 8; ++yy) {
    int ry = yy + 1;
    #pragma unroll
    for (int xi = 0; xi < 4; ++xi) {
      int xx = xg * 4 + xi;
      float s = bias;
      #pragma unroll
      for (int dy = -1; dy <= 1; ++dy)
        #pragma unroll
        for (int dx = -1; dx <= 1; ++dx) {
          int xs = xx + dx;
          float v = (xs >= 0 && xs < 32) ? tile[ry + dy][xs][dl] : 0.f;
          s += v * kk[(dy + 1) * 3 + (dx + 1)];
        }
      float gg = 0.5f * s * (1.0f + erff(s * 0.70710678118654752f));  // exact gelu
      int tok = b * 1024 + (y0 + yy) * 32 + xx;
      hb[(size_t)tok * DHID + d] = f2bf(gg);
      float p0 = gg * g0, p1 = gg * g1;
      for (int m = 16; m; m >>= 1) { p0 += __shfl_xor(p0, m); p1 += __shfl_xor(p1, m); }
      if (dl == 0) {
        part[(size_t)tok * 128 + dc] = p0;
        part[(size_t)tok * 128 + 64 + dc] = p1;
      }
    }
  }
}

// ------------------------- gate 2 reduce (wave per token) -------------------
__global__ void k_gate2(const float* __restrict__ part, unsigned char* __restrict__ pick2) {
  int tok = blockIdx.x * 4 + (threadIdx.x >> 6);
  int l = threadIdx.x & 63;
  const float* pr = part + (size_t)tok * 128;
  float s0 = pr[l], s1 = pr[64 + l];
  for (int m = 32; m; m >>= 1) { s0 += __shfl_xor(s0, m); s1 += __shfl_xor(s1, m); }
  if (l == 0) pick2[tok] = (s0 >= s1) ? 0 : 1;
}

// ------------------------- fc2: gathered bf16 MoE GEMM ----------------------
__launch_bounds__(256, 2)
__global__ void k_fc2(const unsigned short* __restrict__ hb,
                      const unsigned short* __restrict__ w20b,
                      const unsigned short* __restrict__ w21b,
                      const float* __restrict__ b0, const float* __restrict__ b1,
                      const int* __restrict__ perm, const int* __restrict__ n0buf,
                      float* __restrict__ out) {
  __shared__ unsigned short lA[128][32];
  __shared__ unsigned short lB0[128][32];
  __shared__ unsigned short lB1[128][32];
  const int t = threadIdx.x;
  const int wv = t >> 6, ln = t & 63;
  const int lr = ln & 15, lg = ln >> 4;
  const int tok0 = blockIdx.x * 128;
  const int nbase = blockIdx.y * 128;
  const int wm = (wv >> 1) * 64, wn = (wv & 1) * 64;
  const int n0 = n0buf[0];
  const bool do0 = (tok0 < n0);
  const bool do1 = (tok0 + 128 > n0);

  const int swsrc = ((ln & 3) ^ ((ln >> 3) & 3)) << 3;
  const int swrd  = (lg ^ ((lr >> 1) & 3)) << 3;

  int arow[2];
  #pragma unroll
  for (int s = 0; s < 2; ++s)
    arow[s] = perm[tok0 + ((s * 4 + wv) << 4) + (ln >> 2)];

  f32x4 acc0[4][4], acc1[4][4];
  #pragma unroll
  for (int i = 0; i < 4; ++i)
    #pragma unroll
    for (int j = 0; j < 4; ++j) {
      acc0[i][j] = f32x4{0.f, 0.f, 0.f, 0.f};
      acc1[i][j] = f32x4{0.f, 0.f, 0.f, 0.f};
    }

  for (int kt = 0; kt < DHID / 32; ++kt) {
    const int k0 = kt * 32;
    __syncthreads();
    #pragma unroll
    for (int s = 0; s < 2; ++s) {
      int rowblk = s * 4 + wv;
      int row = (rowblk << 4) + (ln >> 2);
      size_t goB = (size_t)(nbase + row) * DHID + k0 + swsrc;
      GLDS16(hb + (size_t)arow[s] * DHID + k0 + swsrc, &lA[rowblk << 4][0]);
      if (do0) GLDS16(w20b + goB, &lB0[rowblk << 4][0]);
      if (do1) GLDS16(w21b + goB, &lB1[rowblk << 4][0]);
    }
    __syncthreads();
    bf16x8 a[4];
    #pragma unroll
    for (int mt = 0; mt < 4; ++mt)
      a[mt] = *(const bf16x8*)(&lA[wm + (mt << 4) + lr][swrd]);
    #pragma unroll
    for (int nt = 0; nt < 4; ++nt) {
      int rB = wn + (nt << 4) + lr;
      if (do0) {
        bf16x8 b0f = *(const bf16x8*)(&lB0[rB][swrd]);
        #pragma unroll
        for (int mt = 0; mt < 4; ++mt)
          acc0[mt][nt] = __builtin_amdgcn_mfma_f32_16x16x32_bf16(a[mt], b0f, acc0[mt][nt], 0, 0, 0);
      }
      if (do1) {
        bf16x8 b1f = *(const bf16x8*)(&lB1[rB][swrd]);
        #pragma unroll
        for (int mt = 0; mt < 4; ++mt)
          acc1[mt][nt] = __builtin_amdgcn_mfma_f32_16x16x32_bf16(a[mt], b1f, acc1[mt][nt], 0, 0, 0);
      }
    }
  }
  #pragma unroll
  for (int nt = 0; nt < 4; ++nt) {
    int c = nbase + wn + (nt << 4) + lr;
    float bi0 = b0[c], bi1 = b1[c];
    #pragma unroll
    for (int mt = 0; mt < 4; ++mt) {
      f32x4 v0 = acc0[mt][nt], v1 = acc1[mt][nt];
      #pragma unroll
      for (int rr = 0; rr < 4; ++rr) {
        int pos = tok0 + wm + (mt << 4) + (lg << 2) + rr;
        int tok = perm[pos];
        float val = (pos >= n0) ? (v1[rr] + bi1) : (v0[rr] + bi0);
        out[(size_t)tok * CIN + c] = val;
      }
    }
  }
}

// ---------------------------------------------------------------------------
extern "C" void kernel_launch(void* const* d_in, const int* in_sizes, int n_in,
                              void* d_out, int out_size, void* d_ws, size_t ws_size,
                              hipStream_t stream) {
  (void)in_sizes; (void)n_in; (void)out_size; (void)ws_size;
  const float* x   = (const float*)d_in[0];
  const float* wg1 = (const float*)d_in[3];
  const float* w0  = (const float*)d_in[4];
  const float* b0  = (const float*)d_in[5];
  const float* w1  = (const float*)d_in[6];
  const float* b1  = (const float*)d_in[7];
  const float* dww = (const float*)d_in[8];
  const float* dwb = (const float*)d_in[9];
  const float* wg2 = (const float*)d_in[10];
  const float* w20 = (const float*)d_in[11];
  const float* b20 = (const float*)d_in[12];
  const float* w21 = (const float*)d_in[13];
  const float* b21 = (const float*)d_in[14];
  float* out = (float*)d_out;

  char* ws = (char*)d_ws;
  const size_t MB2 = 1u << 21;
  unsigned short* w0hi = (unsigned short*)(ws + 0 * MB2);
  unsigned short* w0lo = (unsigned short*)(ws + 1 * MB2);
  unsigned short* w1q  = (unsigned short*)(ws + 2 * MB2);
  unsigned short* w20b = (unsigned short*)(ws + 3 * MB2);
  unsigned short* w21b = (unsigned short*)(ws + 4 * MB2);
  char* p = ws + 5 * MB2;
  unsigned char* pick1 = (unsigned char*)p;            p += 65536;
  unsigned char* pick2 = (unsigned char*)p;            p += 65536;
  int* perm1 = (int*)p;                                p += TOKS * 4;
  int* perm2 = (int*)p;                                p += TOKS * 4;
  int* n0a   = (int*)p;                                p += 256;
  int* n0b   = (int*)p;                                p += 256;
  float* part = (float*)p;                             p += (size_t)TOKS * 128 * 4;
  float* h32  = (float*)p;                             p += (size_t)TOKS * DHID * 4;
  unsigned short* hb = (unsigned short*)p;             // +64 MiB; total ~210 MiB

  k_prep <<<4096, 256, 0, stream>>>(w0, w1, w20, w21, w0hi, w0lo, w1q, w20b, w21b);
  k_gate1<<<4096, 256, 0, stream>>>(x, wg1, pick1);
  k_scan <<<1, 1024, 0, stream>>>(pick1, perm1, n0a);
  k_fc1  <<<dim3(128, 16), 256, 0, stream>>>(x, w0hi, w0lo, w1q, b0, b1, perm1, n0a, h32);
  k_conv <<<dim3(64, 4, 16), 256, 0, stream>>>(h32, dww, dwb, wg2, hb, part);
  k_gate2<<<4096, 256, 0, stream>>>(part, pick2);
  k_scan <<<1, 1024, 0, stream>>>(pick2, perm2, n0b);
  k_fc2  <<<dim3(128, 4), 256, 0, stream>>>(hb, w20b, w21b, b20, b21, perm2, n0b, out);
}